// Round 6
// baseline (456.627 us; speedup 1.0000x reference)
//
#include <hip/hip_runtime.h>
#include <hip/hip_bf16.h>
#include <cstdint>

typedef __bf16 bf16_t;
typedef __bf16 bf16x8 __attribute__((ext_vector_type(8)));
typedef __bf16 bf16x4 __attribute__((ext_vector_type(4)));
typedef float f32x4 __attribute__((ext_vector_type(4)));

#define SEQ    1024
#define BATCH  8
#define NTOK   8192      // BATCH*SEQ
#define DMODEL 1024
#define NHEAD  16
#define HD     64
#define FFDIM  2048

// ---------------------------------------------------------------------------
// async global->LDS, 16B per lane. LDS dest is wave-uniform base + lane*16.
__device__ __forceinline__ void async16(const void* g, void* l) {
  __builtin_amdgcn_global_load_lds(
      (const __attribute__((address_space(1))) void*)g,
      (__attribute__((address_space(3))) void*)l, 16, 0, 0);
}

// ---------------------------------------------------------------------------
__global__ __launch_bounds__(256)
void cast_bf16_kernel(const float* __restrict__ in, bf16_t* __restrict__ out, int n4) {
  int i = blockIdx.x * 256 + threadIdx.x;
  if (i >= n4) return;
  float4 v = ((const float4*)in)[i];
  bf16x4 o = { (bf16_t)v.x, (bf16_t)v.y, (bf16_t)v.z, (bf16_t)v.w };
  *(bf16x4*)&out[(size_t)i * 4] = o;
}

// ---------------------------------------------------------------------------
// transpose + cast: W fp32 [R][C] row-major -> Wt bf16 [C][R] row-major
__global__ __launch_bounds__(256)
void transpose_cast_kernel(const float* __restrict__ W, bf16_t* __restrict__ Wt,
                           int R, int C) {
  __shared__ float tile[32][33];
  const int bx = blockIdx.x * 32;
  const int by = blockIdx.y * 32;
  const int tx = threadIdx.x;
  const int ty = threadIdx.y;
#pragma unroll
  for (int i = 0; i < 4; ++i)
    tile[ty + 8 * i][tx] = W[(size_t)(by + ty + 8 * i) * C + bx + tx];
  __syncthreads();
#pragma unroll
  for (int i = 0; i < 4; ++i)
    Wt[(size_t)(bx + ty + 8 * i) * R + by + tx] = (bf16_t)tile[tx][ty + 8 * i];
}

// ---------------------------------------------------------------------------
// GEMM: C[M,N] = A[M,K] * Bt[N,K]^T (+bias/epilogue), bf16 in, fp32 acc.
// 128x128 tile, BK=64, 256 threads = 4 waves (2x2), each wave 64x64.
// Single-buffered LDS (32 KB -> 4-5 blocks/CU; stalls hidden by TLP, m97/m114
// mechanism). LDS stored in lane-indexed 1KB subtiles: staging lane l writes
// global (row fr=l&15, k (l>>4)*8) at LDS base+l*16B, and every MFMA fragment
// read is exactly base+l*16B (write pattern == read pattern) -> conflict-free.
// 1D grid with bijective XCD swizzle (grid % 8 == 0 always here).
// EPI: 0 = fp32 out +bias; 1 = bf16 relu; 2 = fused QKV epilogue
//      (mode=col>>10: 0 -> Q [b,h,s,e] *qscale, 1 -> K [b,h,s,e], 2 -> V^T [b,h,e,s]).
template <int EPI>
__global__ __launch_bounds__(256)
void gemm_bt(const bf16_t* __restrict__ A, const bf16_t* __restrict__ Bt,
             const float* __restrict__ bias0, const float* __restrict__ bias1,
             const float* __restrict__ bias2,
             void* __restrict__ o0, void* __restrict__ o1, void* __restrict__ o2,
             int K, int nTN, int ldo, float qscale) {
  __shared__ bf16_t As[8192];   // 128 x 64 as 16 lane-indexed subtiles
  __shared__ bf16_t Bs[8192];
  const int tid = threadIdx.x, w = tid >> 6, l = tid & 63;
  const int fr = l & 15, ks = l >> 4;

  // bijective XCD swizzle
  const int nwg = gridDim.x, bid = blockIdx.x;
  const int wg = (bid & 7) * (nwg >> 3) + (bid >> 3);
  const int tm = wg / nTN, tn = wg - tm * nTN;
  const int bm = tm << 7, bn = tn << 7;

  const int wr = (w >> 1) * 64, wc = (w & 1) * 64;
  const int rtA = wr >> 4, rtB = wc >> 4;

  // staging: wave w stages subtiles {4w..4w+3}; subtile s = rows [(s>>1)*16,+16),
  // k-half (s&1)*32. Per-lane src: row fr, k ks*8 (64B segments, 4 lanes each).
  size_t goff[4];
  int lsub[4];
#pragma unroll
  for (int j = 0; j < 4; ++j) {
    const int sub = w * 4 + j, rt = sub >> 1, ct = sub & 1;
    goff[j] = (size_t)(rt * 16 + fr) * K + ct * 32 + ks * 8;
    lsub[j] = sub * 512;
  }

  f32x4 acc[4][4];
#pragma unroll
  for (int i = 0; i < 4; ++i)
#pragma unroll
    for (int j = 0; j < 4; ++j) acc[i][j] = (f32x4){0.f, 0.f, 0.f, 0.f};

  const bf16_t* Ab = A + (size_t)bm * K;
  const bf16_t* Bb = Bt + (size_t)bn * K;

  const int nk = K >> 6;
  for (int kt = 0; kt < nk; ++kt) {
    const int k0 = kt << 6;
#pragma unroll
    for (int j = 0; j < 4; ++j) {
      async16(Ab + k0 + goff[j], &As[lsub[j]]);
      async16(Bb + k0 + goff[j], &Bs[lsub[j]]);
    }
    asm volatile("s_waitcnt vmcnt(0)" ::: "memory");
    __syncthreads();

#pragma unroll
    for (int kk = 0; kk < 2; ++kk) {
      bf16x8 a[4], b[4];
#pragma unroll
      for (int i = 0; i < 4; ++i)
        a[i] = *(const bf16x8*)&As[((rtA + i) * 2 + kk) * 512 + l * 8];
#pragma unroll
      for (int j = 0; j < 4; ++j)
        b[j] = *(const bf16x8*)&Bs[((rtB + j) * 2 + kk) * 512 + l * 8];
#pragma unroll
      for (int i = 0; i < 4; ++i)
#pragma unroll
        for (int j = 0; j < 4; ++j)
          acc[i][j] = __builtin_amdgcn_mfma_f32_16x16x32_bf16(a[i], b[j], acc[i][j], 0, 0, 0);
    }
    __syncthreads();
  }

  // epilogue: C frag mapping col = fr, row = ks*4 + r
  const int lr = ks * 4, lc = fr;
#pragma unroll
  for (int j = 0; j < 4; ++j) {
    const int col = bn + wc + j * 16 + lc;
#pragma unroll
    for (int i = 0; i < 4; ++i) {
#pragma unroll
      for (int r = 0; r < 4; ++r) {
        const int row = bm + wr + i * 16 + lr + r;
        const float v = acc[i][j][r];
        if (EPI == 0) {
          ((float*)o0)[(size_t)row * ldo + col] = v + bias0[col];
        } else if (EPI == 1) {
          ((bf16_t*)o0)[(size_t)row * ldo + col] = (bf16_t)fmaxf(v + bias0[col], 0.f);
        } else {
          const int mode = col >> 10, cl = col & 1023;
          const int b_ = row >> 10, s_ = row & 1023, h_ = cl >> 6, e_ = cl & 63;
          if (mode == 0) {
            ((bf16_t*)o0)[((size_t)((b_ * NHEAD + h_) * SEQ + s_)) * HD + e_] =
                (bf16_t)((v + bias0[cl]) * qscale);
          } else if (mode == 1) {
            ((bf16_t*)o1)[((size_t)((b_ * NHEAD + h_) * SEQ + s_)) * HD + e_] =
                (bf16_t)(v + bias1[cl]);
          } else {
            ((bf16_t*)o2)[((size_t)((b_ * NHEAD + h_) * HD + e_)) * SEQ + s_] =
                (bf16_t)(v + bias2[cl]);
          }
        }
      }
    }
  }
}

// ---------------------------------------------------------------------------
// Flash attention (round-2 version, passing): swizzled K/V/P LDS, dbuf,
// exp2-domain defer-max softmax.
__global__ __launch_bounds__(256)
void attn_kernel(const bf16_t* __restrict__ Q, const bf16_t* __restrict__ K,
                 const bf16_t* __restrict__ VT, bf16_t* __restrict__ CTX) {
  const int bh = blockIdx.x;
  const int qt = blockIdx.y * 128;
  const int b_ = bh >> 4, h_ = bh & 15;
  const bf16_t* qh = Q + (size_t)bh * SEQ * HD;
  const bf16_t* kh = K + (size_t)bh * SEQ * HD;
  const bf16_t* vh = VT + (size_t)bh * HD * SEQ;
  const int tid = threadIdx.x, wave = tid >> 6, lane = tid & 63;
  const int fr = lane & 15, kg = (lane >> 4) * 8;
  const int lr = (lane >> 4) * 4, lc = lane & 15;

  __shared__ bf16_t Ks[2][64 * 64];
  __shared__ bf16_t Vs[2][64 * 64];
  __shared__ bf16_t Ps[128 * 64];

  const int srow = lane >> 3;
  const int scol = ((lane & 7) ^ srow) * 8;

  bf16x8 qf[2][2];
#pragma unroll
  for (int i = 0; i < 2; ++i)
#pragma unroll
    for (int kk = 0; kk < 2; ++kk)
      qf[i][kk] = *(const bf16x8*)&qh[(size_t)(qt + wave * 32 + i * 16 + fr) * HD + kk * 32 + kg];

  f32x4 octx[2][4];
  float mrun[2][4], lrun[2][4];
#pragma unroll
  for (int i = 0; i < 2; ++i)
#pragma unroll
    for (int j = 0; j < 4; ++j) octx[i][j] = (f32x4){0.f, 0.f, 0.f, 0.f};
#pragma unroll
  for (int i = 0; i < 2; ++i)
#pragma unroll
    for (int r = 0; r < 4; ++r) { mrun[i][r] = -1e30f; lrun[i][r] = 0.f; }

  auto stage = [&](int buf, int t) {
#pragma unroll
    for (int i = 0; i < 2; ++i) {
      const int ch = i * 4 + wave;
      const int row = ch * 8 + srow;
      async16(&kh[(size_t)(t * 64 + row) * HD + scol], &Ks[buf][ch * 512]);
      async16(&vh[(size_t)row * SEQ + t * 64 + scol], &Vs[buf][ch * 512]);
    }
  };

  stage(0, 0);
  asm volatile("s_waitcnt vmcnt(0)" ::: "memory");
  __syncthreads();

  for (int t = 0; t < SEQ / 64; ++t) {
    const int cur = t & 1;
    if (t + 1 < SEQ / 64) stage(cur ^ 1, t + 1);

    f32x4 sc[2][4];
#pragma unroll
    for (int i = 0; i < 2; ++i)
#pragma unroll
      for (int j = 0; j < 4; ++j) sc[i][j] = (f32x4){0.f, 0.f, 0.f, 0.f};
#pragma unroll
    for (int kk = 0; kk < 2; ++kk) {
      bf16x8 kf[4];
#pragma unroll
      for (int j = 0; j < 4; ++j) {
        const int row = j * 16 + fr;
        kf[j] = *(const bf16x8*)&Ks[cur][row * 64 + ((kk * 32 + kg) ^ ((row & 7) << 3))];
      }
#pragma unroll
      for (int i = 0; i < 2; ++i)
#pragma unroll
        for (int j = 0; j < 4; ++j)
          sc[i][j] = __builtin_amdgcn_mfma_f32_16x16x32_bf16(qf[i][kk], kf[j], sc[i][j], 0, 0, 0);
    }

    float pmx[2][4];
    int ok = 1;
#pragma unroll
    for (int i = 0; i < 2; ++i)
#pragma unroll
      for (int r = 0; r < 4; ++r) {
        const float m3 = fmaxf(fmaxf(sc[i][0][r], sc[i][1][r]),
                               fmaxf(sc[i][2][r], sc[i][3][r]));
        pmx[i][r] = m3;
        ok &= (m3 <= mrun[i][r] + 8.f) ? 1 : 0;
      }
    if (!__all(ok)) {
#pragma unroll
      for (int i = 0; i < 2; ++i)
#pragma unroll
        for (int r = 0; r < 4; ++r) {
          float mx = pmx[i][r];
#pragma unroll
          for (int m = 1; m < 16; m <<= 1) mx = fmaxf(mx, __shfl_xor(mx, m));
          const float mnew = fmaxf(mrun[i][r], mx);
          const float alpha = exp2f(mrun[i][r] - mnew);
          mrun[i][r] = mnew;
          lrun[i][r] *= alpha;
#pragma unroll
          for (int j = 0; j < 4; ++j) octx[i][j][r] *= alpha;
        }
    }
#pragma unroll
    for (int i = 0; i < 2; ++i)
#pragma unroll
      for (int r = 0; r < 4; ++r) {
        const float m = mrun[i][r];
        float s = 0.f;
#pragma unroll
        for (int j = 0; j < 4; ++j) {
          const float p = exp2f(sc[i][j][r] - m);
          sc[i][j][r] = p;
          s += p;
        }
        lrun[i][r] += s;
        const int prow = wave * 32 + i * 16 + lr + r;
#pragma unroll
        for (int j = 0; j < 4; ++j)
          Ps[prow * 64 + (((j * 16 + lc)) ^ ((prow & 7) << 3))] = (bf16_t)sc[i][j][r];
      }
    asm volatile("s_waitcnt lgkmcnt(0)" ::: "memory");

#pragma unroll
    for (int kk = 0; kk < 2; ++kk) {
      bf16x8 pf[2], vf[4];
#pragma unroll
      for (int i = 0; i < 2; ++i) {
        const int row = wave * 32 + i * 16 + fr;
        pf[i] = *(const bf16x8*)&Ps[row * 64 + ((kk * 32 + kg) ^ ((row & 7) << 3))];
      }
#pragma unroll
      for (int j = 0; j < 4; ++j) {
        const int row = j * 16 + fr;
        vf[j] = *(const bf16x8*)&Vs[cur][row * 64 + ((kk * 32 + kg) ^ ((row & 7) << 3))];
      }
#pragma unroll
      for (int i = 0; i < 2; ++i)
#pragma unroll
        for (int j = 0; j < 4; ++j)
          octx[i][j] = __builtin_amdgcn_mfma_f32_16x16x32_bf16(pf[i], vf[j], octx[i][j], 0, 0, 0);
    }

    asm volatile("s_waitcnt vmcnt(0)" ::: "memory");
    __syncthreads();
  }

#pragma unroll
  for (int i = 0; i < 2; ++i)
#pragma unroll
    for (int r = 0; r < 4; ++r) {
      float lsum = lrun[i][r];
#pragma unroll
      for (int m = 1; m < 16; m <<= 1) lsum += __shfl_xor(lsum, m);
      const float inv = 1.f / lsum;
      const int row = qt + wave * 32 + i * 16 + lr + r;
#pragma unroll
      for (int j = 0; j < 4; ++j) {
        const int c = j * 16 + lc;
        CTX[((size_t)(b_ * SEQ + row)) * DMODEL + h_ * HD + c] = (bf16_t)(octx[i][j][r] * inv);
      }
    }
}

// ---------------------------------------------------------------------------
// LN1: hb = bf16( LN(x + y0) * g + b )
__global__ __launch_bounds__(256)
void ln1_kernel(const float* __restrict__ X, const float* __restrict__ Y0,
                const float* __restrict__ g, const float* __restrict__ b,
                bf16_t* __restrict__ outb) {
  const int row = blockIdx.x, tid = threadIdx.x;
  const int wave = tid >> 6, lane = tid & 63;
  const float4 xv = ((const float4*)X)[(size_t)row * 256 + tid];
  const float4 yv = ((const float4*)Y0)[(size_t)row * 256 + tid];
  const float s0 = xv.x + yv.x, s1 = xv.y + yv.y, s2 = xv.z + yv.z, s3 = xv.w + yv.w;
  float sum = s0 + s1 + s2 + s3;
  float sq = s0 * s0 + s1 * s1 + s2 * s2 + s3 * s3;
#pragma unroll
  for (int off = 1; off < 64; off <<= 1) {
    sum += __shfl_xor(sum, off);
    sq += __shfl_xor(sq, off);
  }
  __shared__ float red[8];
  if (lane == 0) { red[wave] = sum; red[4 + wave] = sq; }
  __syncthreads();
  sum = red[0] + red[1] + red[2] + red[3];
  sq = red[4] + red[5] + red[6] + red[7];
  const float mu = sum * (1.f / 1024.f);
  const float var = sq * (1.f / 1024.f) - mu * mu;
  const float rstd = rsqrtf(var + 1e-5f);
  const float4 gv = ((const float4*)g)[tid];
  const float4 bv = ((const float4*)b)[tid];
  bf16x4 ob = { (bf16_t)((s0 - mu) * rstd * gv.x + bv.x),
                (bf16_t)((s1 - mu) * rstd * gv.y + bv.y),
                (bf16_t)((s2 - mu) * rstd * gv.z + bv.z),
                (bf16_t)((s3 - mu) * rstd * gv.w + bv.w) };
  *(bf16x4*)&outb[(size_t)row * 1024 + tid * 4] = ob;
}

// LN2: out = LN(hb + y0) * g + b
__global__ __launch_bounds__(256)
void ln2_kernel(const bf16_t* __restrict__ Hb, const float* __restrict__ Y0,
                const float* __restrict__ g, const float* __restrict__ b,
                float* __restrict__ outf) {
  const int row = blockIdx.x, tid = threadIdx.x;
  const int wave = tid >> 6, lane = tid & 63;
  const bf16x4 hv = *(const bf16x4*)&Hb[(size_t)row * 1024 + tid * 4];
  const float4 y0 = ((const float4*)Y0)[(size_t)row * 256 + tid];
  const float s0 = (float)hv[0] + y0.x, s1 = (float)hv[1] + y0.y;
  const float s2 = (float)hv[2] + y0.z, s3 = (float)hv[3] + y0.w;
  float sum = s0 + s1 + s2 + s3;
  float sq = s0 * s0 + s1 * s1 + s2 * s2 + s3 * s3;
#pragma unroll
  for (int off = 1; off < 64; off <<= 1) {
    sum += __shfl_xor(sum, off);
    sq += __shfl_xor(sq, off);
  }
  __shared__ float red[8];
  if (lane == 0) { red[wave] = sum; red[4 + wave] = sq; }
  __syncthreads();
  sum = red[0] + red[1] + red[2] + red[3];
  sq = red[4] + red[5] + red[6] + red[7];
  const float mu = sum * (1.f / 1024.f);
  const float var = sq * (1.f / 1024.f) - mu * mu;
  const float rstd = rsqrtf(var + 1e-5f);
  const float4 gv = ((const float4*)g)[tid];
  const float4 bv = ((const float4*)b)[tid];
  ((float4*)outf)[(size_t)row * 256 + tid] =
      make_float4((s0 - mu) * rstd * gv.x + bv.x, (s1 - mu) * rstd * gv.y + bv.y,
                  (s2 - mu) * rstd * gv.z + bv.z, (s3 - mu) * rstd * gv.w + bv.w);
}

// ---------------------------------------------------------------------------
extern "C" void kernel_launch(void* const* d_in, const int* in_sizes, int n_in,
                              void* d_out, int out_size, void* d_ws, size_t ws_size,
                              hipStream_t stream) {
  const float* x   = (const float*)d_in[0];
  const float* Wq  = (const float*)d_in[1];
  const float* bq  = (const float*)d_in[2];
  const float* Wk  = (const float*)d_in[3];
  const float* bk  = (const float*)d_in[4];
  const float* Wv  = (const float*)d_in[5];
  const float* bv  = (const float*)d_in[6];
  const float* Wo  = (const float*)d_in[7];
  const float* bo  = (const float*)d_in[8];
  const float* g1  = (const float*)d_in[9];
  const float* be1 = (const float*)d_in[10];
  const float* W1  = (const float*)d_in[11];
  const float* b1  = (const float*)d_in[12];
  const float* W2  = (const float*)d_in[13];
  const float* b2  = (const float*)d_in[14];
  const float* g2  = (const float*)d_in[15];
  const float* be2 = (const float*)d_in[16];

  char* ws = (char*)d_ws;
  const size_t MB = 1u << 20;
  bf16_t* xb    = (bf16_t*)(ws + 0 * MB);     // 16 MB, x bf16 -> ctx after attn
  bf16_t* WqkvT = (bf16_t*)(ws + 16 * MB);    // 6 MB  [3072][1024]
  bf16_t* WoT   = (bf16_t*)(ws + 22 * MB);    // 2 MB
  bf16_t* W1T   = (bf16_t*)(ws + 24 * MB);    // 4 MB
  bf16_t* W2T   = (bf16_t*)(ws + 28 * MB);    // 4 MB
  bf16_t* qb    = (bf16_t*)(ws + 32 * MB);    // 16 MB -> hb after attn
  bf16_t* kb    = (bf16_t*)(ws + 48 * MB);    // 16 MB \ -> u (32MB) after attn
  bf16_t* vT    = (bf16_t*)(ws + 64 * MB);    // 16 MB /
  float*  y0    = (float*)(ws + 80 * MB);     // 32 MB fp32
  bf16_t* ctx = xb;
  bf16_t* hb  = qb;
  bf16_t* u   = kb;

  // prep
  cast_bf16_kernel<<<dim3(NTOK * DMODEL / 4 / 256), dim3(256), 0, stream>>>(x, xb, NTOK * DMODEL / 4);
  transpose_cast_kernel<<<dim3(32, 32), dim3(32, 8), 0, stream>>>(Wq, WqkvT, 1024, 1024);
  transpose_cast_kernel<<<dim3(32, 32), dim3(32, 8), 0, stream>>>(Wk, WqkvT + 1024 * 1024, 1024, 1024);
  transpose_cast_kernel<<<dim3(32, 32), dim3(32, 8), 0, stream>>>(Wv, WqkvT + 2 * 1024 * 1024, 1024, 1024);
  transpose_cast_kernel<<<dim3(32, 32), dim3(32, 8), 0, stream>>>(Wo, WoT, 1024, 1024);
  transpose_cast_kernel<<<dim3(64, 32), dim3(32, 8), 0, stream>>>(W1, W1T, 1024, 2048);
  transpose_cast_kernel<<<dim3(32, 64), dim3(32, 8), 0, stream>>>(W2, W2T, 2048, 1024);

  const float qscale = 0.125f * 1.44269504088896f;

  // fused QKV: M=8192, N=3072, K=1024 (grid 64x24 = 1536)
  gemm_bt<2><<<dim3(1536), dim3(256), 0, stream>>>(
      xb, WqkvT, bq, bk, bv, qb, kb, vT, 1024, 24, 0, qscale);

  // attention -> ctx (= xb)
  attn_kernel<<<dim3(128, 8), dim3(256), 0, stream>>>(qb, kb, vT, ctx);

  // Wo: M=8192, N=1024, K=1024 (grid 64x8 = 512) -> y0 fp32 (+bo)
  gemm_bt<0><<<dim3(512), dim3(256), 0, stream>>>(
      ctx, WoT, bo, nullptr, nullptr, y0, nullptr, nullptr, 1024, 8, 1024, 1.f);

  // LN1 -> hb (bf16)
  ln1_kernel<<<dim3(NTOK), dim3(256), 0, stream>>>(x, y0, g1, be1, hb);

  // FFN1: M=8192, N=2048, K=1024 (grid 64x16 = 1024) -> u bf16 relu
  gemm_bt<1><<<dim3(1024), dim3(256), 0, stream>>>(
      hb, W1T, b1, nullptr, nullptr, u, nullptr, nullptr, 1024, 16, 2048, 1.f);

  // FFN2: M=8192, N=1024, K=2048 (grid 64x8 = 512) -> y0 fp32
  gemm_bt<0><<<dim3(512), dim3(256), 0, stream>>>(
      u, W2T, b2, nullptr, nullptr, y0, nullptr, nullptr, 2048, 8, 1024, 1.f);

  // LN2 -> d_out
  ln2_kernel<<<dim3(NTOK), dim3(256), 0, stream>>>(hb, y0, g2, be2, (float*)d_out);
}

// Round 7
// 352.114 us; speedup vs baseline: 1.2968x; 1.2968x over previous
//
#include <hip/hip_runtime.h>
#include <hip/hip_bf16.h>
#include <cstdint>

typedef __bf16 bf16_t;
typedef __bf16 bf16x8 __attribute__((ext_vector_type(8)));
typedef __bf16 bf16x4 __attribute__((ext_vector_type(4)));
typedef float f32x4 __attribute__((ext_vector_type(4)));

#define SEQ    1024
#define BATCH  8
#define NTOK   8192      // BATCH*SEQ
#define DMODEL 1024
#define NHEAD  16
#define HD     64
#define FFDIM  2048

// ---------------------------------------------------------------------------
// async global->LDS, 16B per lane. LDS dest is wave-uniform base + lane*16.
__device__ __forceinline__ void async16(const void* g, void* l) {
  __builtin_amdgcn_global_load_lds(
      (const __attribute__((address_space(1))) void*)g,
      (__attribute__((address_space(3))) void*)l, 16, 0, 0);
}

// ---------------------------------------------------------------------------
__global__ __launch_bounds__(256)
void cast_bf16_kernel(const float* __restrict__ in, bf16_t* __restrict__ out, int n4) {
  int i = blockIdx.x * 256 + threadIdx.x;
  if (i >= n4) return;
  float4 v = ((const float4*)in)[i];
  bf16x4 o = { (bf16_t)v.x, (bf16_t)v.y, (bf16_t)v.z, (bf16_t)v.w };
  *(bf16x4*)&out[(size_t)i * 4] = o;
}

// ---------------------------------------------------------------------------
// transpose + cast: W fp32 [R][C] row-major -> Wt bf16 [C][R] row-major
__global__ __launch_bounds__(256)
void transpose_cast_kernel(const float* __restrict__ W, bf16_t* __restrict__ Wt,
                           int R, int C) {
  __shared__ float tile[32][33];
  const int bx = blockIdx.x * 32;
  const int by = blockIdx.y * 32;
  const int tx = threadIdx.x;
  const int ty = threadIdx.y;
#pragma unroll
  for (int i = 0; i < 4; ++i)
    tile[ty + 8 * i][tx] = W[(size_t)(by + ty + 8 * i) * C + bx + tx];
  __syncthreads();
#pragma unroll
  for (int i = 0; i < 4; ++i)
    Wt[(size_t)(bx + ty + 8 * i) * R + by + tx] = (bf16_t)tile[tx][ty + 8 * i];
}

// ---------------------------------------------------------------------------
// GEMM: C[M,N] = A[M,K] * Bt[N,K]^T (+bias/epilogue), bf16 in, fp32 acc.
// r2-proven core: 128x128 tile, BK=64, 256 threads = 4 waves (2x2), each wave
// 64x64; single-buffered 32 KB LDS (~3 blocks/CU -> TLP hides stage drain,
// m97/m114 mechanism). Staging = 8 rows x 128B contiguous per instruction
// with attn-proven XOR swizzle: global col pre-swizzled ((l&7)^(l>>3))*8,
// LDS dest linear, fragment reads XOR (row&7)<<3 -> measured-0 conflicts
// while keeping 128B/row coalescing.
// EPI: 0 = fp32 out +bias; 1 = bf16 relu; 2 = fused QKV epilogue
//      (mode=col>>10: 0 -> Q [b,h,s,e] *qscale, 1 -> K [b,h,s,e], 2 -> V^T).
template <int EPI>
__global__ __launch_bounds__(256)
void gemm_bt(const bf16_t* __restrict__ A, const bf16_t* __restrict__ Bt,
             const float* __restrict__ bias0, const float* __restrict__ bias1,
             const float* __restrict__ bias2,
             void* __restrict__ o0, void* __restrict__ o1, void* __restrict__ o2,
             int K, int ldo, float qscale) {
  __shared__ bf16_t As[8192];   // [128][64] rows of 128B, XOR-swizzled content
  __shared__ bf16_t Bs[8192];
  const int tid = threadIdx.x, w = tid >> 6, l = tid & 63;
  const int fr = l & 15, kg = (l >> 4) * 8;
  const int bm = blockIdx.x << 7, bn = blockIdx.y << 7;
  const int wr = (w >> 1) * 64, wc = (w & 1) * 64;

  // staging geometry (attn pattern): 8-row chunks; lane l -> row +l>>3,
  // global 16B-slot (l&7)^(l>>3); LDS dest linear base + l*16B.
  const int srow = l >> 3;
  const int scol = ((l & 7) ^ srow) * 8;
  const int xork = (fr & 7) << 3;          // read-side XOR (row&7 == fr&7)

  f32x4 acc[4][4];
#pragma unroll
  for (int i = 0; i < 4; ++i)
#pragma unroll
    for (int j = 0; j < 4; ++j) acc[i][j] = (f32x4){0.f, 0.f, 0.f, 0.f};

  const bf16_t* Ab = A + (size_t)bm * K;
  const bf16_t* Bb = Bt + (size_t)bn * K;

  const int nk = K >> 6;
  for (int kt = 0; kt < nk; ++kt) {
    const int k0 = kt << 6;
#pragma unroll
    for (int j = 0; j < 4; ++j) {
      const int ch = w * 4 + j;            // chunk 0..15 = rows [ch*8, ch*8+8)
      const int row = ch * 8 + srow;
      async16(Ab + (size_t)row * K + k0 + scol, &As[ch * 512]);
      async16(Bb + (size_t)row * K + k0 + scol, &Bs[ch * 512]);
    }
    asm volatile("s_waitcnt vmcnt(0)" ::: "memory");
    __syncthreads();

#pragma unroll
    for (int kk = 0; kk < 2; ++kk) {
      bf16x8 a[4], b[4];
      const int ko = (kk * 32 + kg) ^ xork;
#pragma unroll
      for (int i = 0; i < 4; ++i)
        a[i] = *(const bf16x8*)&As[(wr + i * 16 + fr) * 64 + ko];
#pragma unroll
      for (int j = 0; j < 4; ++j)
        b[j] = *(const bf16x8*)&Bs[(wc + j * 16 + fr) * 64 + ko];
#pragma unroll
      for (int i = 0; i < 4; ++i)
#pragma unroll
        for (int j = 0; j < 4; ++j)
          acc[i][j] = __builtin_amdgcn_mfma_f32_16x16x32_bf16(a[i], b[j], acc[i][j], 0, 0, 0);
    }
    __syncthreads();
  }

  // epilogue: C frag mapping col = lane&15, row = (lane>>4)*4 + r
  const int lr = (l >> 4) * 4, lc = fr;
#pragma unroll
  for (int j = 0; j < 4; ++j) {
    const int col = bn + wc + j * 16 + lc;
#pragma unroll
    for (int i = 0; i < 4; ++i) {
#pragma unroll
      for (int r = 0; r < 4; ++r) {
        const int row = bm + wr + i * 16 + lr + r;
        const float v = acc[i][j][r];
        if (EPI == 0) {
          ((float*)o0)[(size_t)row * ldo + col] = v + bias0[col];
        } else if (EPI == 1) {
          ((bf16_t*)o0)[(size_t)row * ldo + col] = (bf16_t)fmaxf(v + bias0[col], 0.f);
        } else {
          const int mode = col >> 10, cl = col & 1023;
          const int b_ = row >> 10, s_ = row & 1023, h_ = cl >> 6, e_ = cl & 63;
          if (mode == 0) {
            ((bf16_t*)o0)[((size_t)((b_ * NHEAD + h_) * SEQ + s_)) * HD + e_] =
                (bf16_t)((v + bias0[cl]) * qscale);
          } else if (mode == 1) {
            ((bf16_t*)o1)[((size_t)((b_ * NHEAD + h_) * SEQ + s_)) * HD + e_] =
                (bf16_t)(v + bias1[cl]);
          } else {
            ((bf16_t*)o2)[((size_t)((b_ * NHEAD + h_) * HD + e_)) * SEQ + s_] =
                (bf16_t)(v + bias2[cl]);
          }
        }
      }
    }
  }
}

// ---------------------------------------------------------------------------
// Flash attention (round-2 version, passing): swizzled K/V/P LDS, dbuf,
// exp2-domain defer-max softmax.
__global__ __launch_bounds__(256)
void attn_kernel(const bf16_t* __restrict__ Q, const bf16_t* __restrict__ K,
                 const bf16_t* __restrict__ VT, bf16_t* __restrict__ CTX) {
  const int bh = blockIdx.x;
  const int qt = blockIdx.y * 128;
  const int b_ = bh >> 4, h_ = bh & 15;
  const bf16_t* qh = Q + (size_t)bh * SEQ * HD;
  const bf16_t* kh = K + (size_t)bh * SEQ * HD;
  const bf16_t* vh = VT + (size_t)bh * HD * SEQ;
  const int tid = threadIdx.x, wave = tid >> 6, lane = tid & 63;
  const int fr = lane & 15, kg = (lane >> 4) * 8;
  const int lr = (lane >> 4) * 4, lc = lane & 15;

  __shared__ bf16_t Ks[2][64 * 64];
  __shared__ bf16_t Vs[2][64 * 64];
  __shared__ bf16_t Ps[128 * 64];

  const int srow = lane >> 3;
  const int scol = ((lane & 7) ^ srow) * 8;

  bf16x8 qf[2][2];
#pragma unroll
  for (int i = 0; i < 2; ++i)
#pragma unroll
    for (int kk = 0; kk < 2; ++kk)
      qf[i][kk] = *(const bf16x8*)&qh[(size_t)(qt + wave * 32 + i * 16 + fr) * HD + kk * 32 + kg];

  f32x4 octx[2][4];
  float mrun[2][4], lrun[2][4];
#pragma unroll
  for (int i = 0; i < 2; ++i)
#pragma unroll
    for (int j = 0; j < 4; ++j) octx[i][j] = (f32x4){0.f, 0.f, 0.f, 0.f};
#pragma unroll
  for (int i = 0; i < 2; ++i)
#pragma unroll
    for (int r = 0; r < 4; ++r) { mrun[i][r] = -1e30f; lrun[i][r] = 0.f; }

  auto stage = [&](int buf, int t) {
#pragma unroll
    for (int i = 0; i < 2; ++i) {
      const int ch = i * 4 + wave;
      const int row = ch * 8 + srow;
      async16(&kh[(size_t)(t * 64 + row) * HD + scol], &Ks[buf][ch * 512]);
      async16(&vh[(size_t)row * SEQ + t * 64 + scol], &Vs[buf][ch * 512]);
    }
  };

  stage(0, 0);
  asm volatile("s_waitcnt vmcnt(0)" ::: "memory");
  __syncthreads();

  for (int t = 0; t < SEQ / 64; ++t) {
    const int cur = t & 1;
    if (t + 1 < SEQ / 64) stage(cur ^ 1, t + 1);

    f32x4 sc[2][4];
#pragma unroll
    for (int i = 0; i < 2; ++i)
#pragma unroll
      for (int j = 0; j < 4; ++j) sc[i][j] = (f32x4){0.f, 0.f, 0.f, 0.f};
#pragma unroll
    for (int kk = 0; kk < 2; ++kk) {
      bf16x8 kf[4];
#pragma unroll
      for (int j = 0; j < 4; ++j) {
        const int row = j * 16 + fr;
        kf[j] = *(const bf16x8*)&Ks[cur][row * 64 + ((kk * 32 + kg) ^ ((row & 7) << 3))];
      }
#pragma unroll
      for (int i = 0; i < 2; ++i)
#pragma unroll
        for (int j = 0; j < 4; ++j)
          sc[i][j] = __builtin_amdgcn_mfma_f32_16x16x32_bf16(qf[i][kk], kf[j], sc[i][j], 0, 0, 0);
    }

    float pmx[2][4];
    int ok = 1;
#pragma unroll
    for (int i = 0; i < 2; ++i)
#pragma unroll
      for (int r = 0; r < 4; ++r) {
        const float m3 = fmaxf(fmaxf(sc[i][0][r], sc[i][1][r]),
                               fmaxf(sc[i][2][r], sc[i][3][r]));
        pmx[i][r] = m3;
        ok &= (m3 <= mrun[i][r] + 8.f) ? 1 : 0;
      }
    if (!__all(ok)) {
#pragma unroll
      for (int i = 0; i < 2; ++i)
#pragma unroll
        for (int r = 0; r < 4; ++r) {
          float mx = pmx[i][r];
#pragma unroll
          for (int m = 1; m < 16; m <<= 1) mx = fmaxf(mx, __shfl_xor(mx, m));
          const float mnew = fmaxf(mrun[i][r], mx);
          const float alpha = exp2f(mrun[i][r] - mnew);
          mrun[i][r] = mnew;
          lrun[i][r] *= alpha;
#pragma unroll
          for (int j = 0; j < 4; ++j) octx[i][j][r] *= alpha;
        }
    }
#pragma unroll
    for (int i = 0; i < 2; ++i)
#pragma unroll
      for (int r = 0; r < 4; ++r) {
        const float m = mrun[i][r];
        float s = 0.f;
#pragma unroll
        for (int j = 0; j < 4; ++j) {
          const float p = exp2f(sc[i][j][r] - m);
          sc[i][j][r] = p;
          s += p;
        }
        lrun[i][r] += s;
        const int prow = wave * 32 + i * 16 + lr + r;
#pragma unroll
        for (int j = 0; j < 4; ++j)
          Ps[prow * 64 + (((j * 16 + lc)) ^ ((prow & 7) << 3))] = (bf16_t)sc[i][j][r];
      }
    asm volatile("s_waitcnt lgkmcnt(0)" ::: "memory");

#pragma unroll
    for (int kk = 0; kk < 2; ++kk) {
      bf16x8 pf[2], vf[4];
#pragma unroll
      for (int i = 0; i < 2; ++i) {
        const int row = wave * 32 + i * 16 + fr;
        pf[i] = *(const bf16x8*)&Ps[row * 64 + ((kk * 32 + kg) ^ ((row & 7) << 3))];
      }
#pragma unroll
      for (int j = 0; j < 4; ++j) {
        const int row = j * 16 + fr;
        vf[j] = *(const bf16x8*)&Vs[cur][row * 64 + ((kk * 32 + kg) ^ ((row & 7) << 3))];
      }
#pragma unroll
      for (int i = 0; i < 2; ++i)
#pragma unroll
        for (int j = 0; j < 4; ++j)
          octx[i][j] = __builtin_amdgcn_mfma_f32_16x16x32_bf16(pf[i], vf[j], octx[i][j], 0, 0, 0);
    }

    asm volatile("s_waitcnt vmcnt(0)" ::: "memory");
    __syncthreads();
  }

#pragma unroll
  for (int i = 0; i < 2; ++i)
#pragma unroll
    for (int r = 0; r < 4; ++r) {
      float lsum = lrun[i][r];
#pragma unroll
      for (int m = 1; m < 16; m <<= 1) lsum += __shfl_xor(lsum, m);
      const float inv = 1.f / lsum;
      const int row = qt + wave * 32 + i * 16 + lr + r;
#pragma unroll
      for (int j = 0; j < 4; ++j) {
        const int c = j * 16 + lc;
        CTX[((size_t)(b_ * SEQ + row)) * DMODEL + h_ * HD + c] = (bf16_t)(octx[i][j][r] * inv);
      }
    }
}

// ---------------------------------------------------------------------------
// LN1: hb = bf16( LN(x + y0) * g + b )
__global__ __launch_bounds__(256)
void ln1_kernel(const float* __restrict__ X, const float* __restrict__ Y0,
                const float* __restrict__ g, const float* __restrict__ b,
                bf16_t* __restrict__ outb) {
  const int row = blockIdx.x, tid = threadIdx.x;
  const int wave = tid >> 6, lane = tid & 63;
  const float4 xv = ((const float4*)X)[(size_t)row * 256 + tid];
  const float4 yv = ((const float4*)Y0)[(size_t)row * 256 + tid];
  const float s0 = xv.x + yv.x, s1 = xv.y + yv.y, s2 = xv.z + yv.z, s3 = xv.w + yv.w;
  float sum = s0 + s1 + s2 + s3;
  float sq = s0 * s0 + s1 * s1 + s2 * s2 + s3 * s3;
#pragma unroll
  for (int off = 1; off < 64; off <<= 1) {
    sum += __shfl_xor(sum, off);
    sq += __shfl_xor(sq, off);
  }
  __shared__ float red[8];
  if (lane == 0) { red[wave] = sum; red[4 + wave] = sq; }
  __syncthreads();
  sum = red[0] + red[1] + red[2] + red[3];
  sq = red[4] + red[5] + red[6] + red[7];
  const float mu = sum * (1.f / 1024.f);
  const float var = sq * (1.f / 1024.f) - mu * mu;
  const float rstd = rsqrtf(var + 1e-5f);
  const float4 gv = ((const float4*)g)[tid];
  const float4 bv = ((const float4*)b)[tid];
  bf16x4 ob = { (bf16_t)((s0 - mu) * rstd * gv.x + bv.x),
                (bf16_t)((s1 - mu) * rstd * gv.y + bv.y),
                (bf16_t)((s2 - mu) * rstd * gv.z + bv.z),
                (bf16_t)((s3 - mu) * rstd * gv.w + bv.w) };
  *(bf16x4*)&outb[(size_t)row * 1024 + tid * 4] = ob;
}

// LN2: out = LN(hb + y0) * g + b
__global__ __launch_bounds__(256)
void ln2_kernel(const bf16_t* __restrict__ Hb, const float* __restrict__ Y0,
                const float* __restrict__ g, const float* __restrict__ b,
                float* __restrict__ outf) {
  const int row = blockIdx.x, tid = threadIdx.x;
  const int wave = tid >> 6, lane = tid & 63;
  const bf16x4 hv = *(const bf16x4*)&Hb[(size_t)row * 1024 + tid * 4];
  const float4 y0 = ((const float4*)Y0)[(size_t)row * 256 + tid];
  const float s0 = (float)hv[0] + y0.x, s1 = (float)hv[1] + y0.y;
  const float s2 = (float)hv[2] + y0.z, s3 = (float)hv[3] + y0.w;
  float sum = s0 + s1 + s2 + s3;
  float sq = s0 * s0 + s1 * s1 + s2 * s2 + s3 * s3;
#pragma unroll
  for (int off = 1; off < 64; off <<= 1) {
    sum += __shfl_xor(sum, off);
    sq += __shfl_xor(sq, off);
  }
  __shared__ float red[8];
  if (lane == 0) { red[wave] = sum; red[4 + wave] = sq; }
  __syncthreads();
  sum = red[0] + red[1] + red[2] + red[3];
  sq = red[4] + red[5] + red[6] + red[7];
  const float mu = sum * (1.f / 1024.f);
  const float var = sq * (1.f / 1024.f) - mu * mu;
  const float rstd = rsqrtf(var + 1e-5f);
  const float4 gv = ((const float4*)g)[tid];
  const float4 bv = ((const float4*)b)[tid];
  ((float4*)outf)[(size_t)row * 256 + tid] =
      make_float4((s0 - mu) * rstd * gv.x + bv.x, (s1 - mu) * rstd * gv.y + bv.y,
                  (s2 - mu) * rstd * gv.z + bv.z, (s3 - mu) * rstd * gv.w + bv.w);
}

// ---------------------------------------------------------------------------
extern "C" void kernel_launch(void* const* d_in, const int* in_sizes, int n_in,
                              void* d_out, int out_size, void* d_ws, size_t ws_size,
                              hipStream_t stream) {
  const float* x   = (const float*)d_in[0];
  const float* Wq  = (const float*)d_in[1];
  const float* bq  = (const float*)d_in[2];
  const float* Wk  = (const float*)d_in[3];
  const float* bk  = (const float*)d_in[4];
  const float* Wv  = (const float*)d_in[5];
  const float* bv  = (const float*)d_in[6];
  const float* Wo  = (const float*)d_in[7];
  const float* bo  = (const float*)d_in[8];
  const float* g1  = (const float*)d_in[9];
  const float* be1 = (const float*)d_in[10];
  const float* W1  = (const float*)d_in[11];
  const float* b1  = (const float*)d_in[12];
  const float* W2  = (const float*)d_in[13];
  const float* b2  = (const float*)d_in[14];
  const float* g2  = (const float*)d_in[15];
  const float* be2 = (const float*)d_in[16];

  char* ws = (char*)d_ws;
  const size_t MB = 1u << 20;
  bf16_t* xb    = (bf16_t*)(ws + 0 * MB);     // 16 MB, x bf16 -> ctx after attn
  bf16_t* WqkvT = (bf16_t*)(ws + 16 * MB);    // 6 MB  [3072][1024]
  bf16_t* WoT   = (bf16_t*)(ws + 22 * MB);    // 2 MB
  bf16_t* W1T   = (bf16_t*)(ws + 24 * MB);    // 4 MB
  bf16_t* W2T   = (bf16_t*)(ws + 28 * MB);    // 4 MB
  bf16_t* qb    = (bf16_t*)(ws + 32 * MB);    // 16 MB -> hb after attn
  bf16_t* kb    = (bf16_t*)(ws + 48 * MB);    // 16 MB \ -> u (32MB) after attn
  bf16_t* vT    = (bf16_t*)(ws + 64 * MB);    // 16 MB /
  float*  y0    = (float*)(ws + 80 * MB);     // 32 MB fp32
  bf16_t* ctx = xb;
  bf16_t* hb  = qb;
  bf16_t* u   = kb;

  // prep
  cast_bf16_kernel<<<dim3(NTOK * DMODEL / 4 / 256), dim3(256), 0, stream>>>(x, xb, NTOK * DMODEL / 4);
  transpose_cast_kernel<<<dim3(32, 32), dim3(32, 8), 0, stream>>>(Wq, WqkvT, 1024, 1024);
  transpose_cast_kernel<<<dim3(32, 32), dim3(32, 8), 0, stream>>>(Wk, WqkvT + 1024 * 1024, 1024, 1024);
  transpose_cast_kernel<<<dim3(32, 32), dim3(32, 8), 0, stream>>>(Wv, WqkvT + 2 * 1024 * 1024, 1024, 1024);
  transpose_cast_kernel<<<dim3(32, 32), dim3(32, 8), 0, stream>>>(Wo, WoT, 1024, 1024);
  transpose_cast_kernel<<<dim3(64, 32), dim3(32, 8), 0, stream>>>(W1, W1T, 1024, 2048);
  transpose_cast_kernel<<<dim3(32, 64), dim3(32, 8), 0, stream>>>(W2, W2T, 2048, 1024);

  const float qscale = 0.125f * 1.44269504088896f;

  // fused QKV: M=8192, N=3072, K=1024 (grid 64x24)
  gemm_bt<2><<<dim3(64, 24), dim3(256), 0, stream>>>(
      xb, WqkvT, bq, bk, bv, qb, kb, vT, 1024, 0, qscale);

  // attention -> ctx (= xb)
  attn_kernel<<<dim3(128, 8), dim3(256), 0, stream>>>(qb, kb, vT, ctx);

  // Wo: M=8192, N=1024, K=1024 (grid 64x8) -> y0 fp32 (+bo)
  gemm_bt<0><<<dim3(64, 8), dim3(256), 0, stream>>>(
      ctx, WoT, bo, nullptr, nullptr, y0, nullptr, nullptr, 1024, 1024, 1.f);

  // LN1 -> hb (bf16)
  ln1_kernel<<<dim3(NTOK), dim3(256), 0, stream>>>(x, y0, g1, be1, hb);

  // FFN1: M=8192, N=2048, K=1024 (grid 64x16) -> u bf16 relu
  gemm_bt<1><<<dim3(64, 16), dim3(256), 0, stream>>>(
      hb, W1T, b1, nullptr, nullptr, u, nullptr, nullptr, 1024, 2048, 1.f);

  // FFN2: M=8192, N=1024, K=2048 (grid 64x8) -> y0 fp32
  gemm_bt<0><<<dim3(64, 8), dim3(256), 0, stream>>>(
      u, W2T, b2, nullptr, nullptr, y0, nullptr, nullptr, 2048, 1024, 1.f);

  // LN2 -> d_out
  ln2_kernel<<<dim3(NTOK), dim3(256), 0, stream>>>(hb, y0, g2, be2, (float*)d_out);
}

// Round 8
// 348.441 us; speedup vs baseline: 1.3105x; 1.0105x over previous
//
#include <hip/hip_runtime.h>
#include <hip/hip_bf16.h>
#include <cstdint>

typedef __bf16 bf16_t;
typedef __bf16 bf16x8 __attribute__((ext_vector_type(8)));
typedef __bf16 bf16x4 __attribute__((ext_vector_type(4)));
typedef float f32x4 __attribute__((ext_vector_type(4)));

#define SEQ    1024
#define BATCH  8
#define NTOK   8192      // BATCH*SEQ
#define DMODEL 1024
#define NHEAD  16
#define HD     64
#define FFDIM  2048

// ---------------------------------------------------------------------------
// async global->LDS, 16B per lane. LDS dest is wave-uniform base + lane*16.
__device__ __forceinline__ void async16(const void* g, void* l) {
  __builtin_amdgcn_global_load_lds(
      (const __attribute__((address_space(1))) void*)g,
      (__attribute__((address_space(3))) void*)l, 16, 0, 0);
}

// ---------------------------------------------------------------------------
__global__ __launch_bounds__(256)
void cast_bf16_kernel(const float* __restrict__ in, bf16_t* __restrict__ out, int n4) {
  int i = blockIdx.x * 256 + threadIdx.x;
  if (i >= n4) return;
  float4 v = ((const float4*)in)[i];
  bf16x4 o = { (bf16_t)v.x, (bf16_t)v.y, (bf16_t)v.z, (bf16_t)v.w };
  *(bf16x4*)&out[(size_t)i * 4] = o;
}

// ---------------------------------------------------------------------------
// transpose + cast: W fp32 [R][C] row-major -> Wt bf16 [C][R] row-major
__global__ __launch_bounds__(256)
void transpose_cast_kernel(const float* __restrict__ W, bf16_t* __restrict__ Wt,
                           int R, int C) {
  __shared__ float tile[32][33];
  const int bx = blockIdx.x * 32;
  const int by = blockIdx.y * 32;
  const int tx = threadIdx.x;
  const int ty = threadIdx.y;
#pragma unroll
  for (int i = 0; i < 4; ++i)
    tile[ty + 8 * i][tx] = W[(size_t)(by + ty + 8 * i) * C + bx + tx];
  __syncthreads();
#pragma unroll
  for (int i = 0; i < 4; ++i)
    Wt[(size_t)(bx + ty + 8 * i) * R + by + tx] = (bf16_t)tile[tx][ty + 8 * i];
}

// ---------------------------------------------------------------------------
// GEMM: C[M,N] = A[M,K] * Bt[N,K]^T (+bias/epilogue), bf16 in, fp32 acc.
// r7 core: 128x128 tile, BK=64, 256 threads = 4 waves (2x2), each wave 64x64;
// single-buffered 32 KB LDS; 8-row x 128B staging with attn-proven XOR
// swizzle (global col pre-swizzled, linear LDS dest, XOR on fragment reads)
// -> 0 bank conflicts with full coalescing.
// NEW: __launch_bounds__(256,4) = 4 waves/EU -> allocator targets <=128 regs
// (64 VGPR + 64 AGPR acc) -> 4 blocks/CU co-resident (was 3). The 2-phase
// structure is stall-bound hidden by TLP (m114); +33% TLP is the lever.
// EPI: 0 = fp32 out +bias (+optional fp32 residual row-add)
//      1 = bf16 relu
//      2 = fused QKV epilogue (mode=col>>10: 0 Q *qscale, 1 K, 2 V^T)
//      3 = fp32 out +bias + bf16 residual row-add
template <int EPI>
__global__ __launch_bounds__(256, 4)
void gemm_bt(const bf16_t* __restrict__ A, const bf16_t* __restrict__ Bt,
             const float* __restrict__ bias0, const float* __restrict__ bias1,
             const float* __restrict__ bias2,
             const float* __restrict__ residF, const bf16_t* __restrict__ residB,
             void* __restrict__ o0, void* __restrict__ o1, void* __restrict__ o2,
             int K, int ldo, float qscale) {
  __shared__ bf16_t As[8192];   // [128][64] rows of 128B, XOR-swizzled content
  __shared__ bf16_t Bs[8192];
  const int tid = threadIdx.x, w = tid >> 6, l = tid & 63;
  const int fr = l & 15, kg = (l >> 4) * 8;
  const int bm = blockIdx.x << 7, bn = blockIdx.y << 7;
  const int wr = (w >> 1) * 64, wc = (w & 1) * 64;

  // staging geometry: 8-row chunks; lane l -> row +l>>3, global 16B-slot
  // (l&7)^(l>>3); LDS dest linear base + l*16B.
  const int srow = l >> 3;
  const int scol = ((l & 7) ^ srow) * 8;
  const int xork = (fr & 7) << 3;          // read-side XOR (row&7 == fr&7)

  f32x4 acc[4][4];
#pragma unroll
  for (int i = 0; i < 4; ++i)
#pragma unroll
    for (int j = 0; j < 4; ++j) acc[i][j] = (f32x4){0.f, 0.f, 0.f, 0.f};

  const bf16_t* Ab = A + (size_t)bm * K;
  const bf16_t* Bb = Bt + (size_t)bn * K;

  const int nk = K >> 6;
  for (int kt = 0; kt < nk; ++kt) {
    const int k0 = kt << 6;
#pragma unroll
    for (int j = 0; j < 4; ++j) {
      const int ch = w * 4 + j;            // chunk 0..15 = rows [ch*8, ch*8+8)
      const int row = ch * 8 + srow;
      async16(Ab + (size_t)row * K + k0 + scol, &As[ch * 512]);
      async16(Bb + (size_t)row * K + k0 + scol, &Bs[ch * 512]);
    }
    asm volatile("s_waitcnt vmcnt(0)" ::: "memory");
    __syncthreads();

#pragma unroll
    for (int kk = 0; kk < 2; ++kk) {
      bf16x8 a[4], b[4];
      const int ko = (kk * 32 + kg) ^ xork;
#pragma unroll
      for (int i = 0; i < 4; ++i)
        a[i] = *(const bf16x8*)&As[(wr + i * 16 + fr) * 64 + ko];
#pragma unroll
      for (int j = 0; j < 4; ++j)
        b[j] = *(const bf16x8*)&Bs[(wc + j * 16 + fr) * 64 + ko];
#pragma unroll
      for (int i = 0; i < 4; ++i)
#pragma unroll
        for (int j = 0; j < 4; ++j)
          acc[i][j] = __builtin_amdgcn_mfma_f32_16x16x32_bf16(a[i], b[j], acc[i][j], 0, 0, 0);
    }
    __syncthreads();
  }

  // epilogue: C frag mapping col = lane&15, row = (lane>>4)*4 + r
  const int lr = (l >> 4) * 4, lc = fr;
#pragma unroll
  for (int j = 0; j < 4; ++j) {
    const int col = bn + wc + j * 16 + lc;
#pragma unroll
    for (int i = 0; i < 4; ++i) {
#pragma unroll
      for (int r = 0; r < 4; ++r) {
        const int row = bm + wr + i * 16 + lr + r;
        const float v = acc[i][j][r];
        if (EPI == 0) {
          float o = v + bias0[col];
          if (residF) o += residF[(size_t)row * ldo + col];
          ((float*)o0)[(size_t)row * ldo + col] = o;
        } else if (EPI == 3) {
          const size_t idx = (size_t)row * ldo + col;
          ((float*)o0)[idx] = v + bias0[col] + (float)residB[idx];
        } else if (EPI == 1) {
          ((bf16_t*)o0)[(size_t)row * ldo + col] = (bf16_t)fmaxf(v + bias0[col], 0.f);
        } else {
          const int mode = col >> 10, cl = col & 1023;
          const int b_ = row >> 10, s_ = row & 1023, h_ = cl >> 6, e_ = cl & 63;
          if (mode == 0) {
            ((bf16_t*)o0)[((size_t)((b_ * NHEAD + h_) * SEQ + s_)) * HD + e_] =
                (bf16_t)((v + bias0[cl]) * qscale);
          } else if (mode == 1) {
            ((bf16_t*)o1)[((size_t)((b_ * NHEAD + h_) * SEQ + s_)) * HD + e_] =
                (bf16_t)(v + bias1[cl]);
          } else {
            ((bf16_t*)o2)[((size_t)((b_ * NHEAD + h_) * HD + e_)) * SEQ + s_] =
                (bf16_t)(v + bias2[cl]);
          }
        }
      }
    }
  }
}

// ---------------------------------------------------------------------------
// Flash attention (round-2 version, passing, untouched): swizzled K/V/P LDS,
// dbuf, exp2-domain defer-max softmax.
__global__ __launch_bounds__(256)
void attn_kernel(const bf16_t* __restrict__ Q, const bf16_t* __restrict__ K,
                 const bf16_t* __restrict__ VT, bf16_t* __restrict__ CTX) {
  const int bh = blockIdx.x;
  const int qt = blockIdx.y * 128;
  const int b_ = bh >> 4, h_ = bh & 15;
  const bf16_t* qh = Q + (size_t)bh * SEQ * HD;
  const bf16_t* kh = K + (size_t)bh * SEQ * HD;
  const bf16_t* vh = VT + (size_t)bh * HD * SEQ;
  const int tid = threadIdx.x, wave = tid >> 6, lane = tid & 63;
  const int fr = lane & 15, kg = (lane >> 4) * 8;
  const int lr = (lane >> 4) * 4, lc = lane & 15;

  __shared__ bf16_t Ks[2][64 * 64];
  __shared__ bf16_t Vs[2][64 * 64];
  __shared__ bf16_t Ps[128 * 64];

  const int srow = lane >> 3;
  const int scol = ((lane & 7) ^ srow) * 8;

  bf16x8 qf[2][2];
#pragma unroll
  for (int i = 0; i < 2; ++i)
#pragma unroll
    for (int kk = 0; kk < 2; ++kk)
      qf[i][kk] = *(const bf16x8*)&qh[(size_t)(qt + wave * 32 + i * 16 + fr) * HD + kk * 32 + kg];

  f32x4 octx[2][4];
  float mrun[2][4], lrun[2][4];
#pragma unroll
  for (int i = 0; i < 2; ++i)
#pragma unroll
    for (int j = 0; j < 4; ++j) octx[i][j] = (f32x4){0.f, 0.f, 0.f, 0.f};
#pragma unroll
  for (int i = 0; i < 2; ++i)
#pragma unroll
    for (int r = 0; r < 4; ++r) { mrun[i][r] = -1e30f; lrun[i][r] = 0.f; }

  auto stage = [&](int buf, int t) {
#pragma unroll
    for (int i = 0; i < 2; ++i) {
      const int ch = i * 4 + wave;
      const int row = ch * 8 + srow;
      async16(&kh[(size_t)(t * 64 + row) * HD + scol], &Ks[buf][ch * 512]);
      async16(&vh[(size_t)row * SEQ + t * 64 + scol], &Vs[buf][ch * 512]);
    }
  };

  stage(0, 0);
  asm volatile("s_waitcnt vmcnt(0)" ::: "memory");
  __syncthreads();

  for (int t = 0; t < SEQ / 64; ++t) {
    const int cur = t & 1;
    if (t + 1 < SEQ / 64) stage(cur ^ 1, t + 1);

    f32x4 sc[2][4];
#pragma unroll
    for (int i = 0; i < 2; ++i)
#pragma unroll
      for (int j = 0; j < 4; ++j) sc[i][j] = (f32x4){0.f, 0.f, 0.f, 0.f};
#pragma unroll
    for (int kk = 0; kk < 2; ++kk) {
      bf16x8 kf[4];
#pragma unroll
      for (int j = 0; j < 4; ++j) {
        const int row = j * 16 + fr;
        kf[j] = *(const bf16x8*)&Ks[cur][row * 64 + ((kk * 32 + kg) ^ ((row & 7) << 3))];
      }
#pragma unroll
      for (int i = 0; i < 2; ++i)
#pragma unroll
        for (int j = 0; j < 4; ++j)
          sc[i][j] = __builtin_amdgcn_mfma_f32_16x16x32_bf16(qf[i][kk], kf[j], sc[i][j], 0, 0, 0);
    }

    float pmx[2][4];
    int ok = 1;
#pragma unroll
    for (int i = 0; i < 2; ++i)
#pragma unroll
      for (int r = 0; r < 4; ++r) {
        const float m3 = fmaxf(fmaxf(sc[i][0][r], sc[i][1][r]),
                               fmaxf(sc[i][2][r], sc[i][3][r]));
        pmx[i][r] = m3;
        ok &= (m3 <= mrun[i][r] + 8.f) ? 1 : 0;
      }
    if (!__all(ok)) {
#pragma unroll
      for (int i = 0; i < 2; ++i)
#pragma unroll
        for (int r = 0; r < 4; ++r) {
          float mx = pmx[i][r];
#pragma unroll
          for (int m = 1; m < 16; m <<= 1) mx = fmaxf(mx, __shfl_xor(mx, m));
          const float mnew = fmaxf(mrun[i][r], mx);
          const float alpha = exp2f(mrun[i][r] - mnew);
          mrun[i][r] = mnew;
          lrun[i][r] *= alpha;
#pragma unroll
          for (int j = 0; j < 4; ++j) octx[i][j][r] *= alpha;
        }
    }
#pragma unroll
    for (int i = 0; i < 2; ++i)
#pragma unroll
      for (int r = 0; r < 4; ++r) {
        const float m = mrun[i][r];
        float s = 0.f;
#pragma unroll
        for (int j = 0; j < 4; ++j) {
          const float p = exp2f(sc[i][j][r] - m);
          sc[i][j][r] = p;
          s += p;
        }
        lrun[i][r] += s;
        const int prow = wave * 32 + i * 16 + lr + r;
#pragma unroll
        for (int j = 0; j < 4; ++j)
          Ps[prow * 64 + (((j * 16 + lc)) ^ ((prow & 7) << 3))] = (bf16_t)sc[i][j][r];
      }
    asm volatile("s_waitcnt lgkmcnt(0)" ::: "memory");

#pragma unroll
    for (int kk = 0; kk < 2; ++kk) {
      bf16x8 pf[2], vf[4];
#pragma unroll
      for (int i = 0; i < 2; ++i) {
        const int row = wave * 32 + i * 16 + fr;
        pf[i] = *(const bf16x8*)&Ps[row * 64 + ((kk * 32 + kg) ^ ((row & 7) << 3))];
      }
#pragma unroll
      for (int j = 0; j < 4; ++j) {
        const int row = j * 16 + fr;
        vf[j] = *(const bf16x8*)&Vs[cur][row * 64 + ((kk * 32 + kg) ^ ((row & 7) << 3))];
      }
#pragma unroll
      for (int i = 0; i < 2; ++i)
#pragma unroll
        for (int j = 0; j < 4; ++j)
          octx[i][j] = __builtin_amdgcn_mfma_f32_16x16x32_bf16(pf[i], vf[j], octx[i][j], 0, 0, 0);
    }

    asm volatile("s_waitcnt vmcnt(0)" ::: "memory");
    __syncthreads();
  }

#pragma unroll
  for (int i = 0; i < 2; ++i)
#pragma unroll
    for (int r = 0; r < 4; ++r) {
      float lsum = lrun[i][r];
#pragma unroll
      for (int m = 1; m < 16; m <<= 1) lsum += __shfl_xor(lsum, m);
      const float inv = 1.f / lsum;
      const int row = qt + wave * 32 + i * 16 + lr + r;
#pragma unroll
      for (int j = 0; j < 4; ++j) {
        const int c = j * 16 + lc;
        CTX[((size_t)(b_ * SEQ + row)) * DMODEL + h_ * HD + c] = (bf16_t)(octx[i][j][r] * inv);
      }
    }
}

// ---------------------------------------------------------------------------
// LN over a single pre-summed fp32 input row; OUTB: 1 = bf16 out, 0 = fp32 out
template <int OUTB>
__global__ __launch_bounds__(256)
void ln_kernel(const float* __restrict__ Y, const float* __restrict__ g,
               const float* __restrict__ b, void* __restrict__ outp) {
  const int row = blockIdx.x, tid = threadIdx.x;
  const int wave = tid >> 6, lane = tid & 63;
  const float4 yv = ((const float4*)Y)[(size_t)row * 256 + tid];
  const float s0 = yv.x, s1 = yv.y, s2 = yv.z, s3 = yv.w;
  float sum = s0 + s1 + s2 + s3;
  float sq = s0 * s0 + s1 * s1 + s2 * s2 + s3 * s3;
#pragma unroll
  for (int off = 1; off < 64; off <<= 1) {
    sum += __shfl_xor(sum, off);
    sq += __shfl_xor(sq, off);
  }
  __shared__ float red[8];
  if (lane == 0) { red[wave] = sum; red[4 + wave] = sq; }
  __syncthreads();
  sum = red[0] + red[1] + red[2] + red[3];
  sq = red[4] + red[5] + red[6] + red[7];
  const float mu = sum * (1.f / 1024.f);
  const float var = sq * (1.f / 1024.f) - mu * mu;
  const float rstd = rsqrtf(var + 1e-5f);
  const float4 gv = ((const float4*)g)[tid];
  const float4 bv = ((const float4*)b)[tid];
  const float o0 = (s0 - mu) * rstd * gv.x + bv.x;
  const float o1 = (s1 - mu) * rstd * gv.y + bv.y;
  const float o2 = (s2 - mu) * rstd * gv.z + bv.z;
  const float o3 = (s3 - mu) * rstd * gv.w + bv.w;
  if (OUTB) {
    bf16x4 ob = { (bf16_t)o0, (bf16_t)o1, (bf16_t)o2, (bf16_t)o3 };
    *(bf16x4*)&((bf16_t*)outp)[(size_t)row * 1024 + tid * 4] = ob;
  } else {
    ((float4*)outp)[(size_t)row * 256 + tid] = make_float4(o0, o1, o2, o3);
  }
}

// ---------------------------------------------------------------------------
extern "C" void kernel_launch(void* const* d_in, const int* in_sizes, int n_in,
                              void* d_out, int out_size, void* d_ws, size_t ws_size,
                              hipStream_t stream) {
  const float* x   = (const float*)d_in[0];
  const float* Wq  = (const float*)d_in[1];
  const float* bq  = (const float*)d_in[2];
  const float* Wk  = (const float*)d_in[3];
  const float* bk  = (const float*)d_in[4];
  const float* Wv  = (const float*)d_in[5];
  const float* bv  = (const float*)d_in[6];
  const float* Wo  = (const float*)d_in[7];
  const float* bo  = (const float*)d_in[8];
  const float* g1  = (const float*)d_in[9];
  const float* be1 = (const float*)d_in[10];
  const float* W1  = (const float*)d_in[11];
  const float* b1  = (const float*)d_in[12];
  const float* W2  = (const float*)d_in[13];
  const float* b2  = (const float*)d_in[14];
  const float* g2  = (const float*)d_in[15];
  const float* be2 = (const float*)d_in[16];

  char* ws = (char*)d_ws;
  const size_t MB = 1u << 20;
  bf16_t* xb    = (bf16_t*)(ws + 0 * MB);     // 16 MB, x bf16 -> ctx after attn
  bf16_t* WqkvT = (bf16_t*)(ws + 16 * MB);    // 6 MB  [3072][1024]
  bf16_t* WoT   = (bf16_t*)(ws + 22 * MB);    // 2 MB
  bf16_t* W1T   = (bf16_t*)(ws + 24 * MB);    // 4 MB
  bf16_t* W2T   = (bf16_t*)(ws + 28 * MB);    // 4 MB
  bf16_t* qb    = (bf16_t*)(ws + 32 * MB);    // 16 MB -> hb after attn
  bf16_t* kb    = (bf16_t*)(ws + 48 * MB);    // 16 MB \ -> u (32MB) after attn
  bf16_t* vT    = (bf16_t*)(ws + 64 * MB);    // 16 MB /
  float*  y0    = (float*)(ws + 80 * MB);     // 32 MB fp32
  bf16_t* ctx = xb;
  bf16_t* hb  = qb;
  bf16_t* u   = kb;

  // prep
  cast_bf16_kernel<<<dim3(NTOK * DMODEL / 4 / 256), dim3(256), 0, stream>>>(x, xb, NTOK * DMODEL / 4);
  transpose_cast_kernel<<<dim3(32, 32), dim3(32, 8), 0, stream>>>(Wq, WqkvT, 1024, 1024);
  transpose_cast_kernel<<<dim3(32, 32), dim3(32, 8), 0, stream>>>(Wk, WqkvT + 1024 * 1024, 1024, 1024);
  transpose_cast_kernel<<<dim3(32, 32), dim3(32, 8), 0, stream>>>(Wv, WqkvT + 2 * 1024 * 1024, 1024, 1024);
  transpose_cast_kernel<<<dim3(32, 32), dim3(32, 8), 0, stream>>>(Wo, WoT, 1024, 1024);
  transpose_cast_kernel<<<dim3(64, 32), dim3(32, 8), 0, stream>>>(W1, W1T, 1024, 2048);
  transpose_cast_kernel<<<dim3(32, 64), dim3(32, 8), 0, stream>>>(W2, W2T, 2048, 1024);

  const float qscale = 0.125f * 1.44269504088896f;

  // fused QKV: M=8192, N=3072, K=1024 (grid 64x24)
  gemm_bt<2><<<dim3(64, 24), dim3(256), 0, stream>>>(
      xb, WqkvT, bq, bk, bv, nullptr, nullptr, qb, kb, vT, 1024, 0, qscale);

  // attention -> ctx (= xb)
  attn_kernel<<<dim3(128, 8), dim3(256), 0, stream>>>(qb, kb, vT, ctx);

  // Wo: y0 = x + ctx@Wo + bo   (residual fused into epilogue)
  gemm_bt<0><<<dim3(64, 8), dim3(256), 0, stream>>>(
      ctx, WoT, bo, nullptr, nullptr, x, nullptr, y0, nullptr, nullptr, 1024, 1024, 1.f);

  // LN1 -> hb (bf16)
  ln_kernel<1><<<dim3(NTOK), dim3(256), 0, stream>>>(y0, g1, be1, hb);

  // FFN1: M=8192, N=2048, K=1024 (grid 64x16) -> u bf16 relu
  gemm_bt<1><<<dim3(64, 16), dim3(256), 0, stream>>>(
      hb, W1T, b1, nullptr, nullptr, nullptr, nullptr, u, nullptr, nullptr, 1024, 2048, 1.f);

  // FFN2: y0 = hb + u@W2 + b2   (bf16 residual fused into epilogue)
  gemm_bt<3><<<dim3(64, 8), dim3(256), 0, stream>>>(
      u, W2T, b2, nullptr, nullptr, nullptr, hb, y0, nullptr, nullptr, 2048, 1024, 1.f);

  // LN2 -> d_out
  ln_kernel<0><<<dim3(NTOK), dim3(256), 0, stream>>>(y0, g2, be2, (float*)d_out);
}